// Round 4
// baseline (260.075 us; speedup 1.0000x reference)
//
#include <hip/hip_runtime.h>

#define NN 384
#define CC 128
#define PP (NN*NN)      // 147456 positions
#define PB 128          // positions per block
#define NB (PP/PB)      // 1152 blocks

typedef __attribute__((ext_vector_type(8))) short bf16x8;
typedef __attribute__((ext_vector_type(4))) float f32x4;
typedef __attribute__((ext_vector_type(8))) unsigned short u16x8;

// weight planes in wfrag, 16384 ushorts (32KB) each
#define PL_APH 0
#define PL_AGH 1
#define PL_BPH 2
#define PL_BGH 3
#define PL_APL 4
#define PL_AGL 5
#define PL_BPL 6
#define PL_BGL 7
#define PL_G   8
#define PL_Z   9

__device__ __forceinline__ unsigned short f2bf(float f){
  unsigned u = __float_as_uint(f);
  u += 0x7FFFu + ((u>>16)&1u);          // RNE
  return (unsigned short)(u>>16);
}
__device__ __forceinline__ float bf2f(unsigned h){
  return __uint_as_float(h<<16);
}
__device__ __forceinline__ unsigned pack2(float a, float b){
  return (unsigned)f2bf(a) | ((unsigned)f2bf(b)<<16);
}
__device__ __forceinline__ float sigmoidf_(float x){
  return __fdividef(1.0f, 1.0f + __expf(-x));
}

// ---------------------------------------------------------------------------
// K0: weights -> bf16 hi/lo planes in MFMA-B-fragment order.
// chunk (k0*8+n)*64+l holds W[n*16+(l&15)][k0*32+(l>>4)*8 .. +7].
// Planes 0-3: hi of ap,ag,bp,bg; 4-7: lo of same; 8: w_g hi; 9: w_z hi.
// hi = bf16(w); lo = bf16(w - float(hi))  -> combined ~17-bit mantissa.
// ---------------------------------------------------------------------------
__global__ __launch_bounds__(256) void k0_wprep(
    const float* __restrict__ wap, const float* __restrict__ wag,
    const float* __restrict__ wbp, const float* __restrict__ wbg,
    const float* __restrict__ wg,  const float* __restrict__ wz,
    unsigned short* __restrict__ wfrag){
  int tid = blockIdx.x*256 + threadIdx.x;      // 0..20479
  int plane = tid >> 11;                       // 0..9
  int chunk = tid & 2047;
  int mat = (plane < 8) ? (plane & 3) : (plane == 8 ? 4 : 5);
  bool lo = (plane >= 4) && (plane < 8);
  const float* W = (mat==0)?wap:(mat==1)?wag:(mat==2)?wbp:(mat==3)?wbg:(mat==4)?wg:wz;
  int k0 = chunk >> 9, n = (chunk >> 6) & 7, l = chunk & 63;
  int o  = n*16 + (l & 15);
  int kb = k0*32 + ((l>>4)<<3);
  const float* s = W + o*128 + kb;
  u16x8 v;
  #pragma unroll
  for (int e=0;e<8;e++){
    float w = s[e];
    unsigned short h = f2bf(w);
    v[e] = lo ? f2bf(w - bf2f(h)) : h;
  }
  *(u16x8*)(wfrag + (size_t)tid*8) = v;
}

// ---------------------------------------------------------------------------
// MFMA helpers. A-frag: row = stripe+(l&15), k = k0*32+(l>>4)*8+e.
// D: row = (l>>4)*4+r, col = l&15 (m89-verified layout).
// ---------------------------------------------------------------------------
// hi/lo pair matmul: acc = bias + A*W with A=aH+aL, W=wH+wL (drop lo*lo)
__device__ __forceinline__ void mm_pair3(const bf16x8 aH[2][4], const bf16x8 aL[2][4],
    const unsigned short* __restrict__ wpH, const unsigned short* __restrict__ wpL,
    const unsigned short* __restrict__ wgH, const unsigned short* __restrict__ wgL,
    const float* __restrict__ bp, const float* __restrict__ bg, int l,
    f32x4 accp[2][8], f32x4 accg[2][8]){
  #pragma unroll
  for (int n=0;n<8;n++){
    float vp = bp[n*16 + (l&15)];
    float vg = bg[n*16 + (l&15)];
    f32x4 ip = {vp,vp,vp,vp}, ig = {vg,vg,vg,vg};
    accp[0][n]=ip; accp[1][n]=ip; accg[0][n]=ig; accg[1][n]=ig;
  }
  #pragma unroll
  for (int k0=0;k0<4;k0++){
    #pragma unroll
    for (int n=0;n<8;n++){
      int co = ((k0*8+n)*64 + l)*8;
      bf16x8 fpH = *(const bf16x8*)(wpH + co);
      bf16x8 fpL = *(const bf16x8*)(wpL + co);
      bf16x8 fgH = *(const bf16x8*)(wgH + co);
      bf16x8 fgL = *(const bf16x8*)(wgL + co);
      #pragma unroll
      for (int m=0;m<2;m++){
        accp[m][n] = __builtin_amdgcn_mfma_f32_16x16x32_bf16(aH[m][k0], fpH, accp[m][n], 0,0,0);
        accp[m][n] = __builtin_amdgcn_mfma_f32_16x16x32_bf16(aH[m][k0], fpL, accp[m][n], 0,0,0);
        accp[m][n] = __builtin_amdgcn_mfma_f32_16x16x32_bf16(aL[m][k0], fpH, accp[m][n], 0,0,0);
        accg[m][n] = __builtin_amdgcn_mfma_f32_16x16x32_bf16(aH[m][k0], fgH, accg[m][n], 0,0,0);
        accg[m][n] = __builtin_amdgcn_mfma_f32_16x16x32_bf16(aH[m][k0], fgL, accg[m][n], 0,0,0);
        accg[m][n] = __builtin_amdgcn_mfma_f32_16x16x32_bf16(aL[m][k0], fgH, accg[m][n], 0,0,0);
      }
    }
  }
}

__device__ __forceinline__ void mm_single(const bf16x8 afr[2][4],
    const unsigned short* __restrict__ wm, const float* __restrict__ bias, int l,
    f32x4 acc[2][8]){
  #pragma unroll
  for (int n=0;n<8;n++){
    float v = bias[n*16 + (l&15)];
    f32x4 iv = {v,v,v,v};
    acc[0][n]=iv; acc[1][n]=iv;
  }
  #pragma unroll
  for (int k0=0;k0<4;k0++){
    #pragma unroll
    for (int n=0;n<8;n++){
      bf16x8 f = *(const bf16x8*)(wm + (((k0*8+n)*64 + l)*8));
      #pragma unroll
      for (int m=0;m<2;m++)
        acc[m][n] = __builtin_amdgcn_mfma_f32_16x16x32_bf16(afr[m][k0], f, acc[m][n], 0,0,0);
    }
  }
}

// ---------------------------------------------------------------------------
// Fused kernel, per 128-position tile:
//  P1  zn = LN(z) f32 -> hi/lo bf16 in bufH/bufL (XOR-swizzled)
//  P2  afrH/afrL fragments
//  P3  a = (zn@Wap^T+bap)*sig(zn@Wag^T+bag)*mask   [f32-grade, kept in regs]
//  P4  b likewise; x = a*b in f32 regs
//  P5  xn = LN(x) in-register (16-lane reduce, two-pass var) -> bufL bf16
//  P6  out = (xn@Wz^T+bz) * sig(zn@Wg^T+bg)        [plain bf16 matmuls]
// ---------------------------------------------------------------------------
__global__ __launch_bounds__(256,2) void k_fused(
    const float* __restrict__ z, const float* __restrict__ mask,
    const float* __restrict__ bap, const float* __restrict__ bag,
    const float* __restrict__ bbp, const float* __restrict__ bbg,
    const float* __restrict__ bgg, const float* __restrict__ bz,
    const float* __restrict__ lniw, const float* __restrict__ lnib,
    const float* __restrict__ lnow, const float* __restrict__ lnob,
    const unsigned short* __restrict__ wfrag,
    float* __restrict__ out){
  __shared__ unsigned char bufH[32768];   // zn hi
  __shared__ unsigned char bufL[32768];   // zn lo, later xn
  const int t = threadIdx.x;
  const int pos0 = blockIdx.x * PB;
  const int rowg = t>>5, c4 = (t&31)<<2;

  // ---- P1: LN(z), two-pass var, hi/lo split ----
  {
    float4 lw = *(const float4*)(lniw + c4);
    float4 lb = *(const float4*)(lnib + c4);
    #pragma unroll
    for (int it=0; it<16; ++it){
      int row = it*8 + rowg;
      float4 v = *(const float4*)(z + (size_t)(pos0+row)*CC + c4);
      float s = v.x+v.y+v.z+v.w;
      #pragma unroll
      for (int mm=1; mm<32; mm<<=1) s += __shfl_xor(s,mm);
      float mu = s*(1.0f/128.0f);
      float d0=v.x-mu, d1=v.y-mu, d2=v.z-mu, d3=v.w-mu;
      float ss = d0*d0+d1*d1+d2*d2+d3*d3;
      #pragma unroll
      for (int mm=1; mm<32; mm<<=1) ss += __shfl_xor(ss,mm);
      float rstd = rsqrtf(ss*(1.0f/128.0f) + 1e-5f);
      float n0=d0*rstd*lw.x+lb.x, n1=d1*rstd*lw.y+lb.y;
      float n2=d2*rstd*lw.z+lb.z, n3=d3*rstd*lw.w+lb.w;
      unsigned short h0=f2bf(n0), h1=f2bf(n1), h2=f2bf(n2), h3=f2bf(n3);
      unsigned off = (unsigned)(row*256 + ((c4<<1) ^ ((row&7)<<4)));
      *(uint2*)(bufH + off) = make_uint2((unsigned)h0|((unsigned)h1<<16),
                                         (unsigned)h2|((unsigned)h3<<16));
      *(uint2*)(bufL + off) = make_uint2(pack2(n0-bf2f(h0), n1-bf2f(h1)),
                                         pack2(n2-bf2f(h2), n3-bf2f(h3)));
    }
  }
  __syncthreads();

  const int wv = t>>6, l = t&63;
  const int cb = l&15;            // D col-within-16 / A row-within-16
  const int g4 = (l>>4)<<2;       // D row-quad base

  // ---- P2: A-fragments (hi and lo) ----
  bf16x8 afrH[2][4], afrL[2][4];
  #pragma unroll
  for (int m=0;m<2;m++){
    #pragma unroll
    for (int k0=0;k0<4;k0++){
      int row = wv*32 + m*16 + cb;
      unsigned off = (unsigned)(row*256 + ((((l>>4)<<4) + (k0<<6)) ^ ((row&7)<<4)));
      afrH[m][k0] = *(const bf16x8*)(bufH + off);
      afrL[m][k0] = *(const bf16x8*)(bufL + off);
    }
  }

  float mk[2][4];
  #pragma unroll
  for (int m=0;m<2;m++)
    #pragma unroll
    for (int r=0;r<4;r++) mk[m][r] = mask[pos0 + wv*32 + m*16 + g4 + r];

  f32x4 accp[2][8], accg[2][8];

  // ---- P3: a (f32-grade) ----
  mm_pair3(afrH, afrL,
           wfrag + PL_APH*16384, wfrag + PL_APL*16384,
           wfrag + PL_AGH*16384, wfrag + PL_AGL*16384,
           bap, bag, l, accp, accg);
  f32x4 xv[2][8];
  #pragma unroll
  for (int m=0;m<2;m++)
    #pragma unroll
    for (int n=0;n<8;n++)
      #pragma unroll
      for (int r=0;r<4;r++)
        xv[m][n][r] = accp[m][n][r]*sigmoidf_(accg[m][n][r])*mk[m][r];

  // ---- P4: b ; x = a*b (all f32) ----
  mm_pair3(afrH, afrL,
           wfrag + PL_BPH*16384, wfrag + PL_BPL*16384,
           wfrag + PL_BGH*16384, wfrag + PL_BGL*16384,
           bbp, bbg, l, accp, accg);
  #pragma unroll
  for (int m=0;m<2;m++)
    #pragma unroll
    for (int n=0;n<8;n++)
      #pragma unroll
      for (int r=0;r<4;r++)
        xv[m][n][r] *= accp[m][n][r]*sigmoidf_(accg[m][n][r])*mk[m][r];

  // ---- P5: LN(x) in-register; rows live on 16-lane groups (masks 1,2,4,8) ----
  float lw8[8], lb8[8];
  #pragma unroll
  for (int n=0;n<8;n++){ lw8[n]=lnow[n*16+cb]; lb8[n]=lnob[n*16+cb]; }
  __syncthreads();                 // all bufL reads (P2) done before xn writes
  #pragma unroll
  for (int m=0;m<2;m++){
    #pragma unroll
    for (int r=0;r<4;r++){
      float s=0.f;
      #pragma unroll
      for (int n=0;n<8;n++) s += xv[m][n][r];
      #pragma unroll
      for (int mm=1; mm<16; mm<<=1) s += __shfl_xor(s,mm);
      float mu = s*(1.0f/128.0f);
      float ss=0.f;
      #pragma unroll
      for (int n=0;n<8;n++){ float d = xv[m][n][r]-mu; ss += d*d; }
      #pragma unroll
      for (int mm=1; mm<16; mm<<=1) ss += __shfl_xor(ss,mm);
      float rstd = rsqrtf(ss*(1.0f/128.0f) + 1e-5f);
      int row = wv*32 + m*16 + g4 + r;
      #pragma unroll
      for (int n=0;n<8;n++){
        int col = n*16 + cb;
        float v = (xv[m][n][r]-mu)*rstd*lw8[n]+lb8[n];
        *(unsigned short*)(bufL + row*256 + ((col<<1) ^ ((row&7)<<4))) = f2bf(v);
      }
    }
  }
  __syncthreads();

  // ---- P6: out = (xn@Wz^T+bz) * sig(zn@Wg^T+bg) ----
  bf16x8 afr2[2][4];
  #pragma unroll
  for (int m=0;m<2;m++){
    #pragma unroll
    for (int k0=0;k0<4;k0++){
      int row = wv*32 + m*16 + cb;
      unsigned off = (unsigned)(row*256 + ((((l>>4)<<4) + (k0<<6)) ^ ((row&7)<<4)));
      afr2[m][k0] = *(const bf16x8*)(bufL + off);
    }
  }
  f32x4 o[2][8], gva[2][8];
  mm_single(afr2, wfrag + PL_Z*16384, bz,  l, o);
  mm_single(afrH, wfrag + PL_G*16384, bgg, l, gva);
  #pragma unroll
  for (int m=0;m<2;m++){
    #pragma unroll
    for (int r=0;r<4;r++){
      int row = wv*32 + m*16 + g4 + r;
      #pragma unroll
      for (int n=0;n<8;n++){
        out[(size_t)(pos0+row)*CC + n*16 + cb] = o[m][n][r]*sigmoidf_(gva[m][n][r]);
      }
    }
  }
}

extern "C" void kernel_launch(void* const* d_in, const int* in_sizes, int n_in,
                              void* d_out, int out_size, void* d_ws, size_t ws_size,
                              hipStream_t stream){
  const float* z     = (const float*)d_in[0];
  const float* mask  = (const float*)d_in[1];
  const float* w_ap  = (const float*)d_in[2];
  const float* b_ap  = (const float*)d_in[3];
  const float* w_bp  = (const float*)d_in[4];
  const float* b_bp  = (const float*)d_in[5];
  const float* w_ag  = (const float*)d_in[6];
  const float* b_ag  = (const float*)d_in[7];
  const float* w_bg  = (const float*)d_in[8];
  const float* b_bg  = (const float*)d_in[9];
  const float* w_g   = (const float*)d_in[10];
  const float* b_g   = (const float*)d_in[11];
  const float* w_z   = (const float*)d_in[12];
  const float* b_z   = (const float*)d_in[13];
  const float* ln_in_w  = (const float*)d_in[14];
  const float* ln_in_b  = (const float*)d_in[15];
  const float* ln_out_w = (const float*)d_in[16];
  const float* ln_out_b = (const float*)d_in[17];

  unsigned short* wfrag = (unsigned short*)d_ws;   // 10 planes * 32KB = 320KB

  k0_wprep<<<80, 256, 0, stream>>>(w_ap, w_ag, w_bp, w_bg, w_g, w_z, wfrag);
  k_fused<<<NB, 256, 0, stream>>>(z, mask, b_ap, b_ag, b_bp, b_bg, b_g, b_z,
                                  ln_in_w, ln_in_b, ln_out_w, ln_out_b,
                                  wfrag, (float*)d_out);
}